// Round 3
// baseline (172.428 us; speedup 1.0000x reference)
//
#include <hip/hip_runtime.h>
#include <hip/hip_bf16.h>

#define W_IMG   128
#define H_IMG   128
#define HW_IMG  16384
#define FX_C    128.0f
#define FY_C    128.0f
#define CX_C    64.0f
#define CY_C    64.0f
#define LOG2E_F 1.4426950408889634f

// ---------------------------------------------------------------------------
// Kernel 1: per-gaussian preprocessing (fp32 inputs).
// Projects each gaussian and precomputes expanded quadratic coefficients so
// the hot loop is 3 FMA + exp2 + 3 FMA + add:
//   w = op * exp(-0.5*dist2/var) = 2^(c0*r2 + c1*X + c2*Y + c3),  r2 = X^2+Y^2
// Layout (AoS, 2 float4 / gaussian): {c0,c1,c2,c3}, {cr,cg,cb,0}
// ---------------------------------------------------------------------------
__global__ __launch_bounds__(256) void prep_kernel(
    const float* __restrict__ pos,
    const float* __restrict__ col,
    const float* __restrict__ opac,
    const float* __restrict__ scl,
    const float* __restrict__ qv,
    const float* __restrict__ tv,
    float4* __restrict__ gout, int N)
{
    int i = blockIdx.x * blockDim.x + threadIdx.x;
    if (i >= N) return;

    float qw = qv[0], qx = qv[1], qy = qv[2], qz = qv[3];
    float qn = sqrtf(qw*qw + qx*qx + qy*qy + qz*qz);
    qw /= qn; qx /= qn; qy /= qn; qz /= qn;

    float R00 = 1.f - 2.f*(qy*qy + qz*qz), R01 = 2.f*(qx*qy - qz*qw), R02 = 2.f*(qx*qz + qy*qw);
    float R10 = 2.f*(qx*qy + qz*qw), R11 = 1.f - 2.f*(qx*qx + qz*qz), R12 = 2.f*(qy*qz - qx*qw);
    float R20 = 2.f*(qx*qz - qy*qw), R21 = 2.f*(qy*qz + qx*qw), R22 = 1.f - 2.f*(qx*qx + qy*qy);

    float t0 = tv[0], t1 = tv[1], t2 = tv[2];

    float x = pos[3*i + 0];
    float y = pos[3*i + 1];
    float z = pos[3*i + 2];

    // cam = R * pos + t   (positions @ R.T row-wise)
    float cx = R00*x + R01*y + R02*z + t0;
    float cy = R10*x + R11*y + R12*z + t1;
    float cz = R20*x + R21*y + R22*z + t2;

    float px = cx / cz * FX_C + CX_C;
    float py = cy / cz * FY_C + CY_C;

    float s   = scl[i];
    float var = s * s;
    float a   = (-0.5f / var) * LOG2E_F;                       // log2-domain scale
    float op  = fmaxf(opac[i], 1e-30f);                        // NaN guard
    float b   = __builtin_amdgcn_logf(op);                     // v_log_f32 = log2(op)

    float4 v0, v1;
    v0.x = a;
    v0.y = -2.f * a * px;
    v0.z = -2.f * a * py;
    v0.w = a * (px*px + py*py) + b;
    v1.x = col[3*i + 0];
    v1.y = col[3*i + 1];
    v1.z = col[3*i + 2];
    v1.w = 0.f;

    gout[2*i + 0] = v0;
    gout[2*i + 1] = v1;
}

// ---------------------------------------------------------------------------
// Kernel 2: the 268M-pair hot loop. grid = (HW/256, nseg); one thread = one
// pixel; each block sweeps segLen gaussians with wave-uniform (scalarizable)
// loads. Each partial slot written exactly once -> no init needed.
// ---------------------------------------------------------------------------
__global__ __launch_bounds__(256) void render_partial(
    const float4* __restrict__ g, float4* __restrict__ part, int segLen)
{
    int p = blockIdx.x * 256 + threadIdx.x;
    float X  = (float)(p & (W_IMG - 1));
    float Y  = (float)(p >> 7);
    float r2 = X*X + Y*Y;

    const float4* gp = g + (size_t)blockIdx.y * segLen * 2;

    float nr = 0.f, ng = 0.f, nb = 0.f, den = 0.f;
    #pragma unroll 4
    for (int j = 0; j < segLen; ++j) {
        float4 v0 = gp[2*j + 0];   // c0,c1,c2,c3  (uniform -> s_load)
        float4 v1 = gp[2*j + 1];   // cr,cg,cb,-
        float arg = fmaf(v0.x, r2, fmaf(v0.y, X, fmaf(v0.z, Y, v0.w)));
        float e   = __builtin_amdgcn_exp2f(arg);   // v_exp_f32
        nr  = fmaf(e, v1.x, nr);
        ng  = fmaf(e, v1.y, ng);
        nb  = fmaf(e, v1.z, nb);
        den += e;
    }

    float4 o; o.x = nr; o.y = ng; o.z = nb; o.w = den;
    part[(size_t)blockIdx.y * HW_IMG + p] = o;
}

// ---------------------------------------------------------------------------
// Kernel 3: reduce segments, add n_chunks*EPS, divide, write tiled/transposed
// FP32 output: out[t, c, s/tile, s%tile], p = t*step + s, step = tile^2.
// ---------------------------------------------------------------------------
__global__ __launch_bounds__(256) void finalize_kernel(
    const float4* __restrict__ part, float* __restrict__ out,
    const int* __restrict__ chunk_gauss_p, const int* __restrict__ tile_hw_p,
    int N, int nseg)
{
    int p = blockIdx.x * 256 + threadIdx.x;

    float nr = 0.f, ng = 0.f, nb = 0.f, den = 0.f;
    for (int s = 0; s < nseg; ++s) {
        float4 v = part[(size_t)s * HW_IMG + p];
        nr += v.x; ng += v.y; nb += v.z; den += v.w;
    }

    int cg = chunk_gauss_p[0];
    int n_chunks = (cg > 0) ? (N / cg) : 0;
    den += (float)n_chunks * 1e-8f;   // EPS added once per scan chunk

    int th   = tile_hw_p[0];
    int step = th * th;
    if (step <= 0 || step > HW_IMG) { th = 64; step = th * th; }  // guard
    int t    = p / step;
    int s2   = p - t * step;
    size_t base = (size_t)t * 3 * step + s2;

    out[base]            = nr / den;
    out[base + step]     = ng / den;
    out[base + 2 * step] = nb / den;
}

extern "C" void kernel_launch(void* const* d_in, const int* in_sizes, int n_in,
                              void* d_out, int out_size, void* d_ws, size_t ws_size,
                              hipStream_t stream)
{
    const float* pos  = (const float*)d_in[0];
    const float* col  = (const float*)d_in[1];
    const float* opac = (const float*)d_in[2];
    const float* scl  = (const float*)d_in[3];
    const float* qv   = (const float*)d_in[4];
    const float* tv   = (const float*)d_in[5];
    const int* tile_hw_p     = (const int*)d_in[6];
    const int* chunk_gauss_p = (const int*)d_in[7];

    int N = in_sizes[2];                 // opacities: one per gaussian

    // Workspace budget: gauss coeffs (N*8 floats) + nseg*HW float4 partials.
    size_t gaussBytes = (size_t)N * 8 * sizeof(float);
    int nseg = 16;
    while (nseg > 1 &&
           gaussBytes + (size_t)nseg * HW_IMG * sizeof(float4) > ws_size)
        nseg >>= 1;
    int segLen = N / nseg;

    float4* gauss = (float4*)d_ws;                          // N * 2 float4
    float4* part  = gauss + (size_t)N * 2;                  // nseg * HW float4

    prep_kernel<<<(N + 255) / 256, 256, 0, stream>>>(pos, col, opac, scl, qv, tv, gauss, N);

    dim3 grid(HW_IMG / 256, nseg);
    render_partial<<<grid, 256, 0, stream>>>(gauss, part, segLen);

    finalize_kernel<<<HW_IMG / 256, 256, 0, stream>>>(
        part, (float*)d_out, chunk_gauss_p, tile_hw_p, N, nseg);
}

// Round 4
// 153.602 us; speedup vs baseline: 1.1226x; 1.1226x over previous
//
#include <hip/hip_runtime.h>

typedef float v2f __attribute__((ext_vector_type(2)));

#define W_IMG   128
#define H_IMG   128
#define HW_IMG  16384
#define FX_C    128.0f
#define FY_C    128.0f
#define CX_C    64.0f
#define CY_C    64.0f
#define LOG2E_F 1.4426950408889634f

// ---------------------------------------------------------------------------
// Kernel 1: per-gaussian preprocessing (fp32 inputs).
// proj[g]   = {px, py, a2, op}  with a2 = -0.5/var * log2(e)
// colors[g] = {cr, cg, cb, 0}
// ---------------------------------------------------------------------------
__global__ __launch_bounds__(256) void prep2_kernel(
    const float* __restrict__ pos,
    const float* __restrict__ col,
    const float* __restrict__ opac,
    const float* __restrict__ scl,
    const float* __restrict__ qv,
    const float* __restrict__ tv,
    float4* __restrict__ proj, float4* __restrict__ colors, int N)
{
    int i = blockIdx.x * blockDim.x + threadIdx.x;
    if (i >= N) return;

    float qw = qv[0], qx = qv[1], qy = qv[2], qz = qv[3];
    float qn = sqrtf(qw*qw + qx*qx + qy*qy + qz*qz);
    qw /= qn; qx /= qn; qy /= qn; qz /= qn;

    float R00 = 1.f - 2.f*(qy*qy + qz*qz), R01 = 2.f*(qx*qy - qz*qw), R02 = 2.f*(qx*qz + qy*qw);
    float R10 = 2.f*(qx*qy + qz*qw), R11 = 1.f - 2.f*(qx*qx + qz*qz), R12 = 2.f*(qy*qz - qx*qw);
    float R20 = 2.f*(qx*qz - qy*qw), R21 = 2.f*(qy*qz + qx*qw), R22 = 1.f - 2.f*(qx*qx + qy*qy);

    float t0 = tv[0], t1 = tv[1], t2 = tv[2];

    float x = pos[3*i + 0];
    float y = pos[3*i + 1];
    float z = pos[3*i + 2];

    float cx = R00*x + R01*y + R02*z + t0;
    float cy = R10*x + R11*y + R12*z + t1;
    float cz = R20*x + R21*y + R22*z + t2;

    float px = cx / cz * FX_C + CX_C;
    float py = cy / cz * FY_C + CY_C;

    float s   = scl[i];
    float var = s * s;
    float a2  = (-0.5f / var) * LOG2E_F;     // log2-domain quadratic scale

    float4 pr; pr.x = px; pr.y = py; pr.z = a2; pr.w = opac[i];
    float4 cl; cl.x = col[3*i+0]; cl.y = col[3*i+1]; cl.z = col[3*i+2]; cl.w = 0.f;
    proj[i]   = pr;
    colors[i] = cl;
}

// ---------------------------------------------------------------------------
// Kernel 2: separable factor tables (4.2M exps total instead of 268M).
//   U[g*128 + x]  = op_g * 2^(a2_g (x-px_g)^2)     (coalesced by x)
//   Vt[y*N + g]   =        2^(a2_g (y-py_g)^2)     (coalesced by g)
// One thread computes one U element and one Vt element.
// ---------------------------------------------------------------------------
__global__ __launch_bounds__(256) void factor_kernel(
    const float4* __restrict__ proj,
    float* __restrict__ U, float* __restrict__ Vt, int N)
{
    int idx = blockIdx.x * 256 + threadIdx.x;   // 0 .. N*128-1

    // U element: gaussian idx>>7, x = idx&127
    float4 pg = proj[idx >> 7];
    float dx = (float)(idx & 127) - pg.x;
    U[idx] = pg.w * __builtin_amdgcn_exp2f(pg.z * dx * dx);

    // Vt element: y = idx / N, g = idx % N
    int yv = idx / N;
    int g2 = idx - yv * N;
    float4 pq = proj[g2];
    float dy = (float)yv - pq.y;
    Vt[idx] = __builtin_amdgcn_exp2f(pq.z * dy * dy);
}

// ---------------------------------------------------------------------------
// Kernel 3 (hot): rank-1 accumulation GEMM. Block = 4 y-rows x 128 x = 512
// pixels, 2 pixels (x-pair) per thread, packed fp32 math. grid=(32, S).
// Per gaussian per thread: 1 float2 load + uniform s_loads + 5 packed VALU.
// ---------------------------------------------------------------------------
__global__ __launch_bounds__(256) void gemm_kernel(
    const float* __restrict__ U, const float* __restrict__ Vt,
    const float4* __restrict__ colors, float4* __restrict__ part,
    int segLen, int N)
{
    int tid = threadIdx.x;
    int x2  = tid & 63;                    // x-pair index: pixels 2*x2, 2*x2+1
    int y   = blockIdx.x * 4 + (tid >> 6); // wave-uniform by construction
    int ys  = __builtin_amdgcn_readfirstlane(y);

    const float* __restrict__ Vrow = Vt + (size_t)ys * N;
    int g0 = blockIdx.y * segLen;

    v2f nr = 0.f, ng = 0.f, nb = 0.f, den = 0.f;

    #pragma unroll 8
    for (int j = 0; j < segLen; ++j) {
        int g = g0 + j;
        v2f   u = *(const v2f*)(U + (size_t)g * 128 + 2 * x2); // vector, coalesced
        float v = Vrow[g];                                      // uniform -> s_load
        float4 c = colors[g];                                   // uniform -> s_load_dwordx4
        v2f w = u * v;                                          // v_pk_mul_f32
        nr  += w * c.x;                                         // v_pk_fma_f32
        ng  += w * c.y;
        nb  += w * c.z;
        den += w;
    }

    int p0 = ys * 128 + 2 * x2;
    size_t base = (size_t)blockIdx.y * HW_IMG + p0;
    float4 o0; o0.x = nr.x; o0.y = ng.x; o0.z = nb.x; o0.w = den.x;
    float4 o1; o1.x = nr.y; o1.y = ng.y; o1.z = nb.y; o1.w = den.y;
    part[base]     = o0;
    part[base + 1] = o1;
}

// ---------------------------------------------------------------------------
// Fallback hot kernel (small-workspace path): direct 2-D evaluation from
// proj/colors, structure identical to the proven round-3 kernel.
// ---------------------------------------------------------------------------
__global__ __launch_bounds__(256) void render_fb(
    const float4* __restrict__ proj, const float4* __restrict__ colors,
    float4* __restrict__ part, int segLen)
{
    int p = blockIdx.x * 256 + threadIdx.x;
    float X = (float)(p & (W_IMG - 1));
    float Y = (float)(p >> 7);

    int g0 = blockIdx.y * segLen;

    float nr = 0.f, ng = 0.f, nb = 0.f, den = 0.f;
    #pragma unroll 4
    for (int j = 0; j < segLen; ++j) {
        int g = g0 + j;
        float4 pg = proj[g];      // uniform -> s_load
        float4 c  = colors[g];
        float dx = X - pg.x;
        float dy = Y - pg.y;
        float d2 = fmaf(dx, dx, dy * dy);
        float e  = pg.w * __builtin_amdgcn_exp2f(pg.z * d2);
        nr  = fmaf(e, c.x, nr);
        ng  = fmaf(e, c.y, ng);
        nb  = fmaf(e, c.z, nb);
        den += e;
    }

    float4 o; o.x = nr; o.y = ng; o.z = nb; o.w = den;
    part[(size_t)blockIdx.y * HW_IMG + p] = o;
}

// ---------------------------------------------------------------------------
// Kernel 4: reduce segments, add n_chunks*EPS, divide, tiled/transposed fp32
// output: out[t, c, s/tile, s%tile], p = t*step + s, step = tile^2.
// ---------------------------------------------------------------------------
__global__ __launch_bounds__(256) void finalize_kernel(
    const float4* __restrict__ part, float* __restrict__ out,
    const int* __restrict__ chunk_gauss_p, const int* __restrict__ tile_hw_p,
    int N, int nseg)
{
    int p = blockIdx.x * 256 + threadIdx.x;

    float nr = 0.f, ng = 0.f, nb = 0.f, den = 0.f;
    for (int s = 0; s < nseg; ++s) {
        float4 v = part[(size_t)s * HW_IMG + p];
        nr += v.x; ng += v.y; nb += v.z; den += v.w;
    }

    int cg = chunk_gauss_p[0];
    int n_chunks = (cg > 0) ? (N / cg) : 0;
    den += (float)n_chunks * 1e-8f;   // EPS added once per scan chunk

    int th   = tile_hw_p[0];
    int step = th * th;
    if (step <= 0 || step > HW_IMG) { th = 64; step = th * th; }
    int t  = p / step;
    int s2 = p - t * step;
    size_t base = (size_t)t * 3 * step + s2;

    out[base]            = nr / den;
    out[base + step]     = ng / den;
    out[base + 2 * step] = nb / den;
}

extern "C" void kernel_launch(void* const* d_in, const int* in_sizes, int n_in,
                              void* d_out, int out_size, void* d_ws, size_t ws_size,
                              hipStream_t stream)
{
    const float* pos  = (const float*)d_in[0];
    const float* col  = (const float*)d_in[1];
    const float* opac = (const float*)d_in[2];
    const float* scl  = (const float*)d_in[3];
    const float* qv   = (const float*)d_in[4];
    const float* tv   = (const float*)d_in[5];
    const int* tile_hw_p     = (const int*)d_in[6];
    const int* chunk_gauss_p = (const int*)d_in[7];

    int N = in_sizes[2];                 // one opacity per gaussian

    // Workspace layout: [proj N f4][colors N f4][U N*128 f][Vt 128*N f][part ...]
    size_t paramsB = (size_t)N * 16 * 2;
    size_t factorB = (size_t)N * 128 * 4 * 2;            // U + Vt

    float4* proj   = (float4*)d_ws;
    float4* colors = proj + N;

    prep2_kernel<<<(N + 255) / 256, 256, 0, stream>>>(
        pos, col, opac, scl, qv, tv, proj, colors, N);

    // Pick factored path if workspace allows (needs ~17-25 MB); else fallback.
    int S = 0;
    for (int cand = 32; cand >= 8; cand >>= 1) {
        if (N % cand == 0 &&
            paramsB + factorB + (size_t)cand * HW_IMG * 16 <= ws_size) { S = cand; break; }
    }

    if (S > 0) {
        float*  U    = (float*)((char*)d_ws + paramsB);
        float*  Vt   = U + (size_t)N * 128;
        float4* part = (float4*)((char*)d_ws + paramsB + factorB);

        factor_kernel<<<(N * 128) / 256, 256, 0, stream>>>(proj, U, Vt, N);

        dim3 grid(H_IMG / 4, S);
        gemm_kernel<<<grid, 256, 0, stream>>>(U, Vt, colors, part, N / S, N);

        finalize_kernel<<<HW_IMG / 256, 256, 0, stream>>>(
            part, (float*)d_out, chunk_gauss_p, tile_hw_p, N, S);
    } else {
        int nseg = 16;
        while (nseg > 1 &&
               (paramsB + (size_t)nseg * HW_IMG * 16 > ws_size || (N % nseg) != 0))
            nseg >>= 1;
        float4* part = (float4*)((char*)d_ws + paramsB);

        dim3 grid(HW_IMG / 256, nseg);
        render_fb<<<grid, 256, 0, stream>>>(proj, colors, part, N / nseg);

        finalize_kernel<<<HW_IMG / 256, 256, 0, stream>>>(
            part, (float*)d_out, chunk_gauss_p, tile_hw_p, N, nseg);
    }
}